// Round 5
// baseline (365.222 us; speedup 1.0000x reference)
//
#include <hip/hip_runtime.h>
#include <hip/hip_bf16.h>
#include <math.h>

// ---------------------------------------------------------------------------
// PMLP_GCN forward:  3x (GEMM -> GCN-agg[+bias]) with BN+ReLU between,
// log_softmax at the end.  N=50000 E=640000 IN=500 HID=128 OUT=64, f32.
// R4: GEMM depth-2 register prefetch (named reg sets, static indexing),
//     W pre-converted to f16 (padded K) once per call.
// ---------------------------------------------------------------------------

#define EPS_BN 1e-5f

typedef __attribute__((ext_vector_type(8))) _Float16 f16x8;
typedef __attribute__((ext_vector_type(4))) _Float16 f16x4;
typedef __attribute__((ext_vector_type(2))) _Float16 f16x2;
typedef __attribute__((ext_vector_type(4))) float    f32x4;

// ---------------- graph prep ----------------

__global__ void count_k(const int* __restrict__ src, const int* __restrict__ dst,
                        int* __restrict__ cnt, int E) {
    int e = blockIdx.x * 256 + threadIdx.x;
    if (e >= E) return;
    int s = src[e], d = dst[e];
    if (s != d) atomicAdd(&cnt[d], 1);
}

__global__ void prep_k(const int* __restrict__ cnt, float* __restrict__ dinv,
                       float* __restrict__ invdeg, int n) {
    int i = blockIdx.x * 256 + threadIdx.x;
    if (i >= n) return;
    float deg = (float)cnt[i] + 1.0f;   // +1 for added self loop
    dinv[i]   = rsqrtf(deg);
    invdeg[i] = 1.0f / deg;
}

// 3-kernel exclusive prefix scan over cnt[n] -> row_start
__global__ void scan1_k(const int* __restrict__ cnt, int* __restrict__ within,
                        int* __restrict__ btot, int n) {
    __shared__ int s[512];
    int tid = threadIdx.x;
    int i = blockIdx.x * 512 + tid;
    int val = (i < n) ? cnt[i] : 0;
    s[tid] = val;
    __syncthreads();
    for (int off = 1; off < 512; off <<= 1) {
        int v = (tid >= off) ? s[tid - off] : 0;
        __syncthreads();
        s[tid] += v;
        __syncthreads();
    }
    if (i < n) within[i] = s[tid] - val;   // exclusive
    if (tid == 511) btot[blockIdx.x] = s[511];
}

__global__ void scan2_k(const int* __restrict__ btot, int* __restrict__ boff, int nblk) {
    if (threadIdx.x == 0) {
        int run = 0;
        for (int b = 0; b < nblk; ++b) { boff[b] = run; run += btot[b]; }
    }
}

__global__ void scan3_k(const int* __restrict__ within, const int* __restrict__ boff,
                        int* __restrict__ row_start, int* __restrict__ cursor, int n) {
    int i = blockIdx.x * 256 + threadIdx.x;
    if (i >= n) return;
    int v = within[i] + boff[i >> 9];
    row_start[i] = v;
    cursor[i]    = v;
}

__global__ void fill_k(const int* __restrict__ src, const int* __restrict__ dst,
                       const float* __restrict__ dinv, int* __restrict__ cursor,
                       int* __restrict__ eidx, float* __restrict__ ew, int E) {
    int e = blockIdx.x * 256 + threadIdx.x;
    if (e >= E) return;
    int s = src[e], d = dst[e];
    if (s == d) return;
    int pos = atomicAdd(&cursor[d], 1);
    eidx[pos] = s;
    ew[pos]   = dinv[s] * dinv[d];
}

// ---- W f32 -> f16 with K padded to Kp (pad zero-filled) ----

__global__ void wcvt_k(const float* __restrict__ W, _Float16* __restrict__ Wh,
                       int rows, int K, int Kp) {
    int q = Kp >> 2;
    int idx = blockIdx.x * 256 + threadIdx.x;
    if (idx >= rows * q) return;
    int r = idx / q, k4 = (idx - r * q) * 4;
    f16x4 h = {(_Float16)0.f, (_Float16)0.f, (_Float16)0.f, (_Float16)0.f};
    if (k4 < K) {                        // K%4==0 -> all-or-none
        float4 v = *(const float4*)(W + (size_t)r * K + k4);
        h[0] = (_Float16)v.x; h[1] = (_Float16)v.y;
        h[2] = (_Float16)v.z; h[3] = (_Float16)v.w;
    }
    *(f16x4*)(Wh + (size_t)r * Kp + k4) = h;
}

// ---------------- MFMA GEMM: C[M,NC] = A[M,K] * Wh[NC,Kp]^T ----------------
// A f32 or f16 (converted in staging); W pre-converted f16 (Kp padded, no
// tail guards). f32 accumulate, f16 out.
// Block: 256 thr = 4 waves; tile 64 x NC; K-chunk 64.
// DEPTH-2 REGISTER PREFETCH: chunk c+3's global loads are issued at iter c
// (named reg sets A/B -> static indexing, no scratch), LDS double-buffered,
// one barrier per chunk. In-flight bytes/wave ~2x vs single prefetch.
// LDS rows 128 B, XOR-swizzled (byte ^= (row&7)<<4): ds_read_b128 2-way max.

template <int NC, bool A_IS_F32>
__global__ __launch_bounds__(256, 4) void mgemm_k(const void* __restrict__ Av,
                                                  const _Float16* __restrict__ Wh,
                                                  _Float16* __restrict__ C,
                                                  int M, int K, int Kp) {
    constexpr int CT = NC / 16;            // col frags per wave
    constexpr int WI = NC / 32;            // W uint4 loads per thread
    __shared__ __align__(16) _Float16 As0[64 * 64];
    __shared__ __align__(16) _Float16 Ws0[NC * 64];
    __shared__ __align__(16) _Float16 As1[64 * 64];
    __shared__ __align__(16) _Float16 Ws1[NC * 64];

    const int tid  = threadIdx.x;
    const int lane = tid & 63, wave = tid >> 6;
    const int lrow = lane & 15, kg = lane >> 4;
    const int row0 = blockIdx.x * 64;

    f32x4 acc[CT] = {};

    float4 awA[4], awB[4];    // A prefetch regs (f32 path)
    uint4  ahA[2], ahB[2];    // A prefetch regs (f16 path)
    uint4  whA[WI], whB[WI];  // W prefetch regs (f16)

    auto load_regs = [&](float4 (&aw)[4], uint4 (&ah)[2], uint4 (&wh)[WI], int c0) {
        const int k0 = c0 * 64;
        if constexpr (A_IS_F32) {
            const float* A = (const float*)Av;
            #pragma unroll
            for (int it = 0; it < 4; ++it) {
                int idx = tid + it * 256;
                int row = idx >> 4, slot = idx & 15;      // 16 float4/row
                int gr = row0 + row, gk = k0 + slot * 4;
                aw[it] = make_float4(0.f, 0.f, 0.f, 0.f);
                if (gr < M && gk < K)                      // K%4==0
                    aw[it] = *(const float4*)(A + (size_t)gr * K + gk);
            }
        } else {
            const _Float16* A = (const _Float16*)Av;
            #pragma unroll
            for (int it = 0; it < 2; ++it) {
                int idx = tid + it * 256;
                int row = idx >> 3, slot = idx & 7;        // 8x 16B/row
                int gr = row0 + row, gk = k0 + slot * 8;
                ah[it] = make_uint4(0u, 0u, 0u, 0u);
                if (gr < M && gk < K)
                    ah[it] = *(const uint4*)(A + (size_t)gr * K + gk);
            }
        }
        #pragma unroll
        for (int it = 0; it < WI; ++it) {                  // NC x 8 slots, no guard
            int idx = tid + it * 256;
            int row = idx >> 3, slot = idx & 7;
            wh[it] = *(const uint4*)(Wh + (size_t)row * Kp + k0 + slot * 8);
        }
    };

    auto write_lds = [&](char* AsB, char* WsB,
                         float4 (&aw)[4], uint4 (&ah)[2], uint4 (&wh)[WI]) {
        if constexpr (A_IS_F32) {
            #pragma unroll
            for (int it = 0; it < 4; ++it) {
                int idx = tid + it * 256;
                int row = idx >> 4, slot = idx & 15;
                f16x4 h;
                h[0] = (_Float16)aw[it].x; h[1] = (_Float16)aw[it].y;
                h[2] = (_Float16)aw[it].z; h[3] = (_Float16)aw[it].w;
                int cb = (slot * 8) ^ ((row & 7) << 4);
                *(f16x4*)(AsB + row * 128 + cb) = h;
            }
        } else {
            #pragma unroll
            for (int it = 0; it < 2; ++it) {
                int idx = tid + it * 256;
                int row = idx >> 3, slot = idx & 7;
                int cb = (slot * 16) ^ ((row & 7) << 4);
                *(uint4*)(AsB + row * 128 + cb) = ah[it];
            }
        }
        #pragma unroll
        for (int it = 0; it < WI; ++it) {
            int idx = tid + it * 256;
            int row = idx >> 3, slot = idx & 7;
            int cb = (slot * 16) ^ ((row & 7) << 4);
            *(uint4*)(WsB + row * 128 + cb) = wh[it];
        }
    };

    auto compute = [&](const char* AsB, const char* WsB) {
        #pragma unroll
        for (int ks = 0; ks < 2; ++ks) {
            const int cbase = ks * 64 + kg * 16;
            f16x8 af, bf[CT];
            {
                int row = wave * 16 + lrow;
                af = *(const f16x8*)(AsB + row * 128 + (cbase ^ ((row & 7) << 4)));
            }
            #pragma unroll
            for (int ct = 0; ct < CT; ++ct) {
                int row = ct * 16 + lrow;
                bf[ct] = *(const f16x8*)(WsB + row * 128 + (cbase ^ ((row & 7) << 4)));
            }
            #pragma unroll
            for (int ct = 0; ct < CT; ++ct)
                acc[ct] = __builtin_amdgcn_mfma_f32_16x16x32_f16(
                    af, bf[ct], acc[ct], 0, 0, 0);
        }
    };

    const int nchunk = Kp >> 6;            // Kp % 64 == 0, nchunk >= 2
    // prologue: chunks 0,1 -> regs; chunk0 -> LDS0; chunk2 -> regs A
    load_regs(awA, ahA, whA, 0);
    load_regs(awB, ahB, whB, 1);
    write_lds((char*)As0, (char*)Ws0, awA, ahA, whA);
    if (nchunk > 2) load_regs(awA, ahA, whA, 2);
    __syncthreads();

    int c = 0;
    while (true) {
        compute((const char*)As0, (const char*)Ws0);       // chunk c
        if (c + 1 >= nchunk) break;
        write_lds((char*)As1, (char*)Ws1, awB, ahB, whB);  // chunk c+1
        if (c + 3 < nchunk) load_regs(awB, ahB, whB, c + 3);
        __syncthreads();

        compute((const char*)As1, (const char*)Ws1);       // chunk c+1
        if (c + 2 >= nchunk) break;
        write_lds((char*)As0, (char*)Ws0, awA, ahA, whA);  // chunk c+2
        if (c + 4 < nchunk) load_regs(awA, ahA, whA, c + 4);
        __syncthreads();
        c += 2;
    }

    // ---- epilogue: D lane map col=lane&15, row=(lane>>4)*4+r ----
    #pragma unroll
    for (int r = 0; r < 4; ++r) {
        int grow = row0 + wave * 16 + kg * 4 + r;
        if (grow >= M) continue;
        #pragma unroll
        for (int ct = 0; ct < CT; ++ct)
            C[(size_t)grow * NC + ct * 16 + lrow] = (_Float16)acc[ct][r];
    }
}

// ---------------- GCN aggregation (gather over CSR, f16 rows) ----------------
// out[i] = sum_{e: dst=i} w_e * h[src_e] + invdeg[i]*h[i] + bias
// One wave per node, 4 nodes per 256-thread block, 4-edge unroll.

__global__ void agg128_k(const _Float16* __restrict__ h, const float* __restrict__ invdeg,
                         const int* __restrict__ row_start, const int* __restrict__ cnt,
                         const int* __restrict__ eidx, const float* __restrict__ ew,
                         const float* __restrict__ bias, float* __restrict__ out, int n) {
    const int wv = threadIdx.x >> 6, lane = threadIdx.x & 63;
    const int i = blockIdx.x * 4 + wv;
    if (i >= n) return;
    const int st = row_start[i], en = st + cnt[i];
    const float id = invdeg[i];
    const int c = lane * 2;

    f16x2 hv = *(const f16x2*)(h + (size_t)i * 128 + c);
    float a0 = fmaf(id, (float)hv[0], bias[c]);
    float a1 = fmaf(id, (float)hv[1], bias[c + 1]);
    int p = st;
    for (; p + 3 < en; p += 4) {
        int s0 = eidx[p], s1 = eidx[p + 1], s2 = eidx[p + 2], s3 = eidx[p + 3];
        float w0 = ew[p], w1 = ew[p + 1], w2 = ew[p + 2], w3 = ew[p + 3];
        f16x2 v0 = *(const f16x2*)(h + (size_t)s0 * 128 + c);
        f16x2 v1 = *(const f16x2*)(h + (size_t)s1 * 128 + c);
        f16x2 v2 = *(const f16x2*)(h + (size_t)s2 * 128 + c);
        f16x2 v3 = *(const f16x2*)(h + (size_t)s3 * 128 + c);
        a0 = fmaf(w0, (float)v0[0], a0); a1 = fmaf(w0, (float)v0[1], a1);
        a0 = fmaf(w1, (float)v1[0], a0); a1 = fmaf(w1, (float)v1[1], a1);
        a0 = fmaf(w2, (float)v2[0], a0); a1 = fmaf(w2, (float)v2[1], a1);
        a0 = fmaf(w3, (float)v3[0], a0); a1 = fmaf(w3, (float)v3[1], a1);
    }
    for (; p < en; ++p) {
        int s0 = eidx[p]; float w0 = ew[p];
        f16x2 v0 = *(const f16x2*)(h + (size_t)s0 * 128 + c);
        a0 = fmaf(w0, (float)v0[0], a0); a1 = fmaf(w0, (float)v0[1], a1);
    }
    out[(size_t)i * 128 + c]     = a0;
    out[(size_t)i * 128 + c + 1] = a1;
}

// ---- classifier agg (64 cols) with log_softmax fused (row == wave) ----

__global__ void aggsm_k(const _Float16* __restrict__ h, const float* __restrict__ invdeg,
                        const int* __restrict__ row_start, const int* __restrict__ cnt,
                        const int* __restrict__ eidx, const float* __restrict__ ew,
                        const float* __restrict__ bias, float* __restrict__ out, int n) {
    const int wv = threadIdx.x >> 6, lane = threadIdx.x & 63;
    const int i = blockIdx.x * 4 + wv;
    if (i >= n) return;
    const int st = row_start[i], en = st + cnt[i];
    const float id = invdeg[i];

    float a0 = fmaf(id, (float)h[(size_t)i * 64 + lane], bias[lane]);
    int p = st;
    for (; p + 3 < en; p += 4) {
        int s0 = eidx[p], s1 = eidx[p + 1], s2 = eidx[p + 2], s3 = eidx[p + 3];
        float w0 = ew[p], w1 = ew[p + 1], w2 = ew[p + 2], w3 = ew[p + 3];
        float v0 = (float)h[(size_t)s0 * 64 + lane];
        float v1 = (float)h[(size_t)s1 * 64 + lane];
        float v2 = (float)h[(size_t)s2 * 64 + lane];
        float v3 = (float)h[(size_t)s3 * 64 + lane];
        a0 = fmaf(w0, v0, a0); a0 = fmaf(w1, v1, a0);
        a0 = fmaf(w2, v2, a0); a0 = fmaf(w3, v3, a0);
    }
    for (; p < en; ++p)
        a0 = fmaf(ew[p], (float)h[(size_t)eidx[p] * 64 + lane], a0);

    // fused log_softmax over the 64-wide row held by this wave
    float m = a0;
    #pragma unroll
    for (int d = 32; d >= 1; d >>= 1) m = fmaxf(m, __shfl_xor(m, d, 64));
    float e = __expf(a0 - m);
    float s = e;
    #pragma unroll
    for (int d = 32; d >= 1; d >>= 1) s += __shfl_xor(s, d, 64);
    out[(size_t)i * 64 + lane] = a0 - m - __logf(s);
}

// ---------------- BatchNorm (affine=False) + ReLU ----------------

__global__ void stats_k(const float* __restrict__ a, float* __restrict__ gsum,
                        float* __restrict__ gsq, int n) {
    __shared__ float ls[256], lq[256];
    int tid = threadIdx.x;
    int c = tid & 127, g = tid >> 7;
    float s = 0.f, q = 0.f;
    for (int row = blockIdx.x * 2 + g; row < n; row += gridDim.x * 2) {
        float v = a[row * 128 + c];
        s += v; q += v * v;
    }
    ls[tid] = s; lq[tid] = q;
    __syncthreads();
    if (tid < 128) {
        atomicAdd(&gsum[c], ls[tid] + ls[tid + 128]);
        atomicAdd(&gsq[c],  lq[tid] + lq[tid + 128]);
    }
}

__global__ void finalize_k(const float* __restrict__ gsum, const float* __restrict__ gsq,
                           float* __restrict__ scale, float* __restrict__ shift, int n) {
    int c = threadIdx.x;   // 128
    float mean = gsum[c] / (float)n;
    float var  = gsq[c] / (float)n - mean * mean;
    float sc   = rsqrtf(var + EPS_BN);
    scale[c] = sc;
    shift[c] = -mean * sc;
}

// BN scale/shift + ReLU, f32 in -> f16 out (only consumer is the next GEMM)
__global__ void norm_k(const float* __restrict__ a, _Float16* __restrict__ o,
                       const float* __restrict__ scale, const float* __restrict__ shift,
                       int total4) {
    int idx = blockIdx.x * 256 + threadIdx.x;
    if (idx >= total4) return;
    float4 v = ((const float4*)a)[idx];
    int c0 = (idx & 31) * 4;
    f16x4 h;
    h[0] = (_Float16)fmaxf(0.f, fmaf(v.x, scale[c0 + 0], shift[c0 + 0]));
    h[1] = (_Float16)fmaxf(0.f, fmaf(v.y, scale[c0 + 1], shift[c0 + 1]));
    h[2] = (_Float16)fmaxf(0.f, fmaf(v.z, scale[c0 + 2], shift[c0 + 2]));
    h[3] = (_Float16)fmaxf(0.f, fmaf(v.w, scale[c0 + 3], shift[c0 + 3]));
    *(f16x4*)(o + (size_t)idx * 4) = h;
}

// ---------------------------------------------------------------------------

extern "C" void kernel_launch(void* const* d_in, const int* in_sizes, int n_in,
                              void* d_out, int out_size, void* d_ws, size_t ws_size,
                              hipStream_t stream) {
    const float* x  = (const float*)d_in[0];
    const int*   ei = (const int*)d_in[1];
    const float* W0 = (const float*)d_in[2];
    const float* b0 = (const float*)d_in[3];
    const float* W1 = (const float*)d_in[4];
    const float* b1 = (const float*)d_in[5];
    const float* W2 = (const float*)d_in[6];
    const float* b2 = (const float*)d_in[7];

    const int IN = 500;
    const int n = in_sizes[0] / IN;      // 50000
    const int E = in_sizes[1] / 2;       // 640000
    const int* src = ei;
    const int* dst = ei + E;

    // ---- workspace bump allocator (256B aligned) ----
    char* p = (char*)d_ws;
    auto alloc = [&](size_t bytes) -> void* {
        char* r = p;
        p += (bytes + 255) & ~(size_t)255;
        return (void*)r;
    };
    _Float16*  hb1h    = (_Float16*)alloc((size_t)n * 128 * 2); // GEMM out / agg in
    float*     hb2     = (float*)alloc((size_t)n * 128 * 4);    // agg out / BN in
    _Float16*  hb2h    = (_Float16*)alloc((size_t)n * 128 * 2); // BN out / GEMM in
    _Float16*  W0h     = (_Float16*)alloc((size_t)128 * 512 * 2);
    _Float16*  W1h     = (_Float16*)alloc((size_t)128 * 128 * 2);
    _Float16*  W2h     = (_Float16*)alloc((size_t)64 * 128 * 2);
    int*   deg_cnt  = (int*)alloc((size_t)n * 4);
    float* dinv     = (float*)alloc((size_t)n * 4);
    float* invdeg   = (float*)alloc((size_t)n * 4);
    int*   row_st   = (int*)alloc((size_t)n * 4);
    int*   cursor   = (int*)alloc((size_t)n * 4);
    int*   within   = (int*)alloc((size_t)n * 4);
    int*   btot     = (int*)alloc(256 * 4);
    int*   boff     = (int*)alloc(256 * 4);
    int*   eidx     = (int*)alloc((size_t)E * 4);
    float* ew       = (float*)alloc((size_t)E * 4);
    float* gsum     = (float*)alloc(128 * 4);   // gsum+gsq contiguous: one memset
    float* gsq      = (float*)alloc(128 * 4);
    float* scale    = (float*)alloc(128 * 4);
    float* shift    = (float*)alloc(128 * 4);
    (void)ws_size; (void)n_in; (void)out_size;

    float* out = (float*)d_out;

    const int gE = (E + 255) / 256;
    const int gN = (n + 255) / 256;
    const int nblk = (n + 511) / 512;
    const int gM = (n + 63) / 64;        // 782 blocks
    const int gA = (n + 3) / 4;          // 12500 blocks

    // ---- graph prep + weight conversion (once per call) ----
    hipMemsetAsync(deg_cnt, 0, (size_t)n * 4, stream);
    count_k<<<gE, 256, 0, stream>>>(src, dst, deg_cnt, E);
    prep_k<<<gN, 256, 0, stream>>>(deg_cnt, dinv, invdeg, n);
    scan1_k<<<nblk, 512, 0, stream>>>(deg_cnt, within, btot, n);
    scan2_k<<<1, 64, 0, stream>>>(btot, boff, nblk);
    scan3_k<<<gN, 256, 0, stream>>>(within, boff, row_st, cursor, n);
    fill_k<<<gE, 256, 0, stream>>>(src, dst, dinv, cursor, eidx, ew, E);
    wcvt_k<<<(128 * 512 / 4 + 255) / 256, 256, 0, stream>>>(W0, W0h, 128, 500, 512);
    wcvt_k<<<(128 * 128 / 4 + 255) / 256, 256, 0, stream>>>(W1, W1h, 128, 128, 128);
    wcvt_k<<<(64 * 128 / 4 + 255) / 256, 256, 0, stream>>>(W2, W2h, 64, 128, 128);

    // ---- layer 0 ----
    mgemm_k<128, true><<<gM, 256, 0, stream>>>(x, W0h, hb1h, n, 500, 512);
    agg128_k<<<gA, 256, 0, stream>>>(hb1h, invdeg, row_st, deg_cnt, eidx, ew, b0, hb2, n);
    hipMemsetAsync(gsum, 0, 256 * 4, stream);
    stats_k<<<256, 256, 0, stream>>>(hb2, gsum, gsq, n);
    finalize_k<<<1, 128, 0, stream>>>(gsum, gsq, scale, shift, n);
    norm_k<<<(n * 32 + 255) / 256, 256, 0, stream>>>(hb2, hb2h, scale, shift, n * 32);

    // ---- layer 1 ----
    mgemm_k<128, false><<<gM, 256, 0, stream>>>(hb2h, W1h, hb1h, n, 128, 128);
    agg128_k<<<gA, 256, 0, stream>>>(hb1h, invdeg, row_st, deg_cnt, eidx, ew, b1, hb2, n);
    hipMemsetAsync(gsum, 0, 256 * 4, stream);
    stats_k<<<256, 256, 0, stream>>>(hb2, gsum, gsq, n);
    finalize_k<<<1, 128, 0, stream>>>(gsum, gsq, scale, shift, n);
    norm_k<<<(n * 32 + 255) / 256, 256, 0, stream>>>(hb2, hb2h, scale, shift, n * 32);

    // ---- classifier (log_softmax fused into agg) ----
    mgemm_k<64, false><<<gM, 256, 0, stream>>>(hb2h, W2h, hb1h, n, 128, 128);
    aggsm_k<<<gA, 256, 0, stream>>>(hb1h, invdeg, row_st, deg_cnt, eidx, ew, b2, out, n);
}